// Round 1
// baseline (301.383 us; speedup 1.0000x reference)
//
#include <hip/hip_runtime.h>

// TSP_GNN: 2x GCNConv(edge-weighted, self-loops) + FC + row softmax.
// N=8192 nodes, E=262144 edges, H=64.
// Pipeline: CSR build -> X@W1 (split-bf16 MFMA, streaming) -> agg1 ->
//           x@W2 (fp32) -> agg2(+bf16 cast) -> rowsum(exp) -> write softmax.

#define NN 8192
#define NE 262144
#define HD 64

typedef float f32x4 __attribute__((ext_vector_type(4)));
typedef short v8s   __attribute__((ext_vector_type(8)));
typedef unsigned short ushort_t;

__device__ __forceinline__ unsigned short bf16_rne(float f){
  union { float f; unsigned u; } v; v.f = f;
  unsigned r = v.u + 0x7fffu + ((v.u >> 16) & 1u);
  return (unsigned short)(r >> 16);
}
__device__ __forceinline__ float bf16_f32(unsigned short h){
  union { unsigned u; float f; } v; v.u = ((unsigned)h) << 16;
  return v.f;
}
__device__ __forceinline__ f32x4 mfma16(v8s a, v8s b, f32x4 c){
  return __builtin_amdgcn_mfma_f32_16x16x32_bf16(a, b, c, 0, 0, 0);
}

// ---------------- graph prep ----------------
__global__ void k_init(float* deg, int* cnt, int* wcnt, float* S){
  int i = blockIdx.x*blockDim.x + threadIdx.x;
  if (i < NN){ deg[i]=1.0f; cnt[i]=0; wcnt[i]=0; S[i]=0.0f; }
}

__global__ void k_deg_cnt(const int* ei, const float* ew, float* deg, int* cnt){
  int e = blockIdx.x*blockDim.x + threadIdx.x;
  if (e < NE){
    int d = ei[NE + e];                 // edge_index[1][e] = dst
    atomicAdd(&deg[d], ew[e]);          // deg = 1 (self loop) + sum of in-edge weights
    atomicAdd(&cnt[d], 1);
  }
}

__global__ void k_dinv(const float* deg, float* dinv){
  int i = blockIdx.x*blockDim.x + threadIdx.x;
  if (i < NN) dinv[i] = 1.0f / sqrtf(deg[i]);
}

// single-block exclusive scan of 8192 counts -> rowptr
__global__ void k_scan(const int* cnt, int* rowptr){
  __shared__ int part[256];
  int t = threadIdx.x;
  int loc[32]; int s = 0;
  #pragma unroll
  for (int j=0;j<32;++j){ loc[j] = cnt[t*32+j]; s += loc[j]; }
  part[t] = s; __syncthreads();
  for (int off=1; off<256; off<<=1){
    int v = (t >= off) ? part[t-off] : 0;
    __syncthreads();
    part[t] += v;
    __syncthreads();
  }
  int run = part[t] - s;                // exclusive prefix
  #pragma unroll
  for (int j=0;j<32;++j){ rowptr[t*32+j] = run; run += loc[j]; }
  if (t == 255) rowptr[NN] = run;       // = NE
}

__global__ void k_fill(const int* ei, const float* ew, const float* dinv,
                       const int* rowptr, int* wcnt, int* csr_src, float* csr_nrm){
  int e = blockIdx.x*blockDim.x + threadIdx.x;
  if (e < NE){
    int s = ei[e], d = ei[NE+e];
    int slot = rowptr[d] + atomicAdd(&wcnt[d], 1);
    csr_src[slot] = s;
    csr_nrm[slot] = dinv[s] * ew[e] * dinv[d];
  }
}

// ---------------- weight packing ----------------
// W1 [8192][64] fp32 -> hi/lo bf16, B-fragment layout:
// idx = ((kb*4 + nt)*16 + c)*32 + kk   (k = kb*32+kk, col = nt*16+c)
__global__ void k_pack_w1(const float* W1, ushort_t* w1hi, ushort_t* w1lo){
  int idx = blockIdx.x*blockDim.x + threadIdx.x;
  if (idx < NN*HD){
    int kk = idx & 31, c = (idx>>5)&15, nt = (idx>>9)&3, kb = idx>>11;
    int k = kb*32 + kk, col = nt*16 + c;
    float w = W1[(size_t)k*HD + col];
    unsigned short hi = bf16_rne(w);
    w1hi[idx] = hi;
    w1lo[idx] = bf16_rne(w - bf16_f32(hi));
  }
}

// fcW [64][8192] fp32 -> bf16, B-fragment layout:
// idx = ((kb*512 + cblk)*16 + c)*32 + kk   (k = kb*32+kk, col = cblk*16+c)
__global__ void k_pack_fcw(const float* fcW, ushort_t* fcwp){
  int idx = blockIdx.x*blockDim.x + threadIdx.x;
  if (idx < HD*NN){
    int kk = idx & 31, c = (idx>>5)&15, cblk = (idx>>9)&511, kb = idx>>18;
    int k = kb*32 + kk, col = cblk*16 + c;
    fcwp[idx] = bf16_rne(fcW[(size_t)k*NN + col]);
  }
}

// ---------------- GEMM1: xw1 = X @ W1 ----------------
// block = 512 thr (8 waves), 32 rows/block, each wave owns K/8 = 1024.
// A-fragments loaded straight from global (lane l&15 = row, l>>4 = 8-k segment),
// converted to bf16 hi/lo in-register; 3-MFMA split for ~fp32 accuracy.
__global__ __launch_bounds__(512) void k_gemm1(const float* __restrict__ X,
                                               const ushort_t* __restrict__ w1hi,
                                               const ushort_t* __restrict__ w1lo,
                                               float* __restrict__ xw1){
  int tid = threadIdx.x, lane = tid & 63, w = tid >> 6;
  int r = lane & 15, seg = lane >> 4;
  int row0 = blockIdx.x * 32;
  const float* xr0 = X + (size_t)(row0 + r)     * NN + seg*8;
  const float* xr1 = X + (size_t)(row0 + 16 + r)* NN + seg*8;
  int kbase = w * 1024;

  f32x4 z = {0.f,0.f,0.f,0.f};
  f32x4 acc0[4] = {z,z,z,z};
  f32x4 acc1[4] = {z,z,z,z};

  f32x4 p00 = *(const f32x4*)(xr0 + kbase);
  f32x4 p01 = *(const f32x4*)(xr0 + kbase + 4);
  f32x4 p10 = *(const f32x4*)(xr1 + kbase);
  f32x4 p11 = *(const f32x4*)(xr1 + kbase + 4);

  for (int it = 0; it < 32; ++it){
    int k0 = kbase + it*32;
    int kb = k0 >> 5;
    f32x4 c00=p00, c01=p01, c10=p10, c11=p11;
    if (it < 31){
      int kn = k0 + 32;
      p00 = *(const f32x4*)(xr0 + kn);
      p01 = *(const f32x4*)(xr0 + kn + 4);
      p10 = *(const f32x4*)(xr1 + kn);
      p11 = *(const f32x4*)(xr1 + kn + 4);
    }
    v8s a0h, a0l, a1h, a1l;
    #pragma unroll
    for (int j=0;j<4;++j){
      float f = c00[j]; unsigned short h = bf16_rne(f);
      a0h[j] = (short)h; a0l[j] = (short)bf16_rne(f - bf16_f32(h));
      f = c01[j]; h = bf16_rne(f);
      a0h[4+j] = (short)h; a0l[4+j] = (short)bf16_rne(f - bf16_f32(h));
      f = c10[j]; h = bf16_rne(f);
      a1h[j] = (short)h; a1l[j] = (short)bf16_rne(f - bf16_f32(h));
      f = c11[j]; h = bf16_rne(f);
      a1h[4+j] = (short)h; a1l[4+j] = (short)bf16_rne(f - bf16_f32(h));
    }
    #pragma unroll
    for (int nt=0; nt<4; ++nt){
      size_t boff = ((size_t)(kb*4 + nt)*16 + r)*32 + seg*8;
      v8s bh = *(const v8s*)(w1hi + boff);
      v8s bl = *(const v8s*)(w1lo + boff);
      acc0[nt] = mfma16(a0h, bh, acc0[nt]);
      acc0[nt] = mfma16(a0h, bl, acc0[nt]);
      acc0[nt] = mfma16(a0l, bh, acc0[nt]);
      acc1[nt] = mfma16(a1h, bh, acc1[nt]);
      acc1[nt] = mfma16(a1h, bl, acc1[nt]);
      acc1[nt] = mfma16(a1l, bh, acc1[nt]);
    }
  }

  // reduce 8 K-partials via LDS
  __shared__ float red[8][32][64];   // 64 KB
  #pragma unroll
  for (int nt=0; nt<4; ++nt)
    #pragma unroll
    for (int j=0;j<4;++j){
      red[w][4*seg + j][nt*16 + r]      = acc0[nt][j];
      red[w][16 + 4*seg + j][nt*16 + r] = acc1[nt][j];
    }
  __syncthreads();
  for (int o = tid; o < 32*64; o += 512){
    int rr = o >> 6, cc = o & 63;
    float s = 0.f;
    #pragma unroll
    for (int ww=0; ww<8; ++ww) s += red[ww][rr][cc];
    xw1[(size_t)(row0 + rr)*HD + cc] = s;
  }
}

// ---------------- aggregation (per conv) ----------------
// 1 wave per node, lane = h. out = dinv^2*x[i] + sum_e norm*x[src] + b, relu.
__global__ __launch_bounds__(256) void k_agg(const float* __restrict__ xin,
                                             const float* __restrict__ bias,
                                             const float* __restrict__ dinv,
                                             const int* __restrict__ rowptr,
                                             const int* __restrict__ csr_src,
                                             const float* __restrict__ csr_nrm,
                                             float* outf, ushort_t* outb, int mode){
  int lane = threadIdx.x & 63, w = threadIdx.x >> 6;
  int i = blockIdx.x*4 + w;
  float di = dinv[i];
  float acc = di*di * xin[(size_t)i*HD + lane];
  int e = rowptr[i], e1 = rowptr[i+1];
  for (; e + 1 < e1; e += 2){
    int s0 = csr_src[e], s1 = csr_src[e+1];
    float n0 = csr_nrm[e], n1 = csr_nrm[e+1];
    acc += n0 * xin[(size_t)s0*HD + lane];
    acc += n1 * xin[(size_t)s1*HD + lane];
  }
  if (e < e1) acc += csr_nrm[e] * xin[(size_t)csr_src[e]*HD + lane];
  float v = acc + bias[lane];
  v = v > 0.f ? v : 0.f;
  if (mode == 0) outf[(size_t)i*HD + lane] = v;
  else           outb[(size_t)i*HD + lane] = bf16_rne(v);
}

// ---------------- conv2 GEMM: x2w = x1a @ W2 (fp32, K=64) ----------------
__global__ __launch_bounds__(64) void k_conv2(const float* __restrict__ x1a,
                                              const float* __restrict__ W2,
                                              float* __restrict__ x2w){
  int i = blockIdx.x, h = threadIdx.x;
  __shared__ float xs[64];
  xs[h] = x1a[(size_t)i*HD + h];
  __syncthreads();
  float acc = 0.f;
  #pragma unroll
  for (int k=0;k<64;++k) acc += xs[k] * W2[k*HD + h];
  x2w[(size_t)i*HD + h] = acc;
}

// ---------------- FC + softmax (two recompute passes) ----------------
// tile: block = 4 waves, wave = 32 rows x 64 cols, 4 col-iters (256 cols/block)
__global__ __launch_bounds__(256) void k_rowsum(const ushort_t* __restrict__ x2b,
                                                const ushort_t* __restrict__ fcwp,
                                                const float* __restrict__ fcb,
                                                float* __restrict__ S){
  int lane = threadIdx.x & 63, w = threadIdx.x >> 6;
  int r = lane & 15, seg = lane >> 4;
  int row0 = blockIdx.x*128 + w*32;
  const ushort_t* xb = x2b + (size_t)(row0 + r)*HD + seg*8;
  v8s a00 = *(const v8s*)(xb);
  v8s a01 = *(const v8s*)(xb + 32);
  v8s a10 = *(const v8s*)(xb + 16*HD);
  v8s a11 = *(const v8s*)(xb + 16*HD + 32);
  float rp0[4] = {0,0,0,0}, rp1[4] = {0,0,0,0};
  for (int cb=0; cb<4; ++cb){
    int colbase = blockIdx.y*256 + cb*64;
    f32x4 z = {0.f,0.f,0.f,0.f};
    f32x4 acc0[4] = {z,z,z,z}, acc1[4] = {z,z,z,z};
    #pragma unroll
    for (int nt=0; nt<4; ++nt){
      int cblk = (colbase >> 4) + nt;
      v8s bA = *(const v8s*)(fcwp + ((size_t)cblk*16 + r)*32 + seg*8);
      v8s bB = *(const v8s*)(fcwp + ((size_t)(512 + cblk)*16 + r)*32 + seg*8);
      acc0[nt] = mfma16(a00, bA, acc0[nt]);
      acc0[nt] = mfma16(a01, bB, acc0[nt]);
      acc1[nt] = mfma16(a10, bA, acc1[nt]);
      acc1[nt] = mfma16(a11, bB, acc1[nt]);
    }
    #pragma unroll
    for (int nt=0; nt<4; ++nt){
      int col = colbase + nt*16 + r;
      float fb = fcb[col];
      #pragma unroll
      for (int j=0;j<4;++j){
        rp0[j] += __expf(acc0[nt][j] + fb);
        rp1[j] += __expf(acc1[nt][j] + fb);
      }
    }
  }
  #pragma unroll
  for (int m=1; m<16; m<<=1)
    #pragma unroll
    for (int j=0;j<4;++j){
      rp0[j] += __shfl_xor(rp0[j], m);
      rp1[j] += __shfl_xor(rp1[j], m);
    }
  if (r == 0){
    #pragma unroll
    for (int j=0;j<4;++j){
      atomicAdd(&S[row0 + 4*seg + j],      rp0[j]);
      atomicAdd(&S[row0 + 16 + 4*seg + j], rp1[j]);
    }
  }
}

__global__ void k_sinv(const float* S, float* Sinv){
  int i = blockIdx.x*blockDim.x + threadIdx.x;
  if (i < NN) Sinv[i] = 1.0f / S[i];
}

__global__ __launch_bounds__(256) void k_passB(const ushort_t* __restrict__ x2b,
                                               const ushort_t* __restrict__ fcwp,
                                               const float* __restrict__ fcb,
                                               const float* __restrict__ Sinv,
                                               float* __restrict__ out){
  int lane = threadIdx.x & 63, w = threadIdx.x >> 6;
  int r = lane & 15, seg = lane >> 4;
  int row0 = blockIdx.x*128 + w*32;
  const ushort_t* xb = x2b + (size_t)(row0 + r)*HD + seg*8;
  v8s a00 = *(const v8s*)(xb);
  v8s a01 = *(const v8s*)(xb + 32);
  v8s a10 = *(const v8s*)(xb + 16*HD);
  v8s a11 = *(const v8s*)(xb + 16*HD + 32);
  float si0[4], si1[4];
  #pragma unroll
  for (int j=0;j<4;++j){
    si0[j] = Sinv[row0 + 4*seg + j];
    si1[j] = Sinv[row0 + 16 + 4*seg + j];
  }
  for (int cb=0; cb<4; ++cb){
    int colbase = blockIdx.y*256 + cb*64;
    f32x4 z = {0.f,0.f,0.f,0.f};
    f32x4 acc0[4] = {z,z,z,z}, acc1[4] = {z,z,z,z};
    #pragma unroll
    for (int nt=0; nt<4; ++nt){
      int cblk = (colbase >> 4) + nt;
      v8s bA = *(const v8s*)(fcwp + ((size_t)cblk*16 + r)*32 + seg*8);
      v8s bB = *(const v8s*)(fcwp + ((size_t)(512 + cblk)*16 + r)*32 + seg*8);
      acc0[nt] = mfma16(a00, bA, acc0[nt]);
      acc0[nt] = mfma16(a01, bB, acc0[nt]);
      acc1[nt] = mfma16(a10, bA, acc1[nt]);
      acc1[nt] = mfma16(a11, bB, acc1[nt]);
    }
    #pragma unroll
    for (int nt=0; nt<4; ++nt){
      int col = colbase + nt*16 + r;
      float fb = fcb[col];
      #pragma unroll
      for (int j=0;j<4;++j){
        out[(size_t)(row0 + 4*seg + j)*NN + col]      = __expf(acc0[nt][j] + fb) * si0[j];
        out[(size_t)(row0 + 16 + 4*seg + j)*NN + col] = __expf(acc1[nt][j] + fb) * si1[j];
      }
    }
  }
}

// ---------------- host ----------------
extern "C" void kernel_launch(void* const* d_in, const int* in_sizes, int n_in,
                              void* d_out, int out_size, void* d_ws, size_t ws_size,
                              hipStream_t stream){
  (void)in_sizes; (void)n_in; (void)out_size; (void)ws_size;
  const int*   ei  = (const int*)  d_in[0];
  const float* ew  = (const float*)d_in[1];
  const float* X   = (const float*)d_in[2];
  const float* W1  = (const float*)d_in[3];
  const float* b1  = (const float*)d_in[4];
  const float* W2  = (const float*)d_in[5];
  const float* b2  = (const float*)d_in[6];
  const float* fcW = (const float*)d_in[7];
  const float* fcb = (const float*)d_in[8];
  float* out = (float*)d_out;
  char*  ws  = (char*)d_ws;

  float*    deg     = (float*)   (ws + 0);
  float*    dinv    = (float*)   (ws + 32768);
  int*      cnt     = (int*)     (ws + 65536);
  int*      wcnt    = (int*)     (ws + 98304);
  int*      rowptr  = (int*)     (ws + 131072);
  int*      csr_src = (int*)     (ws + 167936);
  float*    csr_nrm = (float*)   (ws + 1216512);
  ushort_t* w1hi    = (ushort_t*)(ws + 2265088);
  ushort_t* w1lo    = (ushort_t*)(ws + 3313664);
  ushort_t* fcwp    = (ushort_t*)(ws + 4362240);
  float*    xw1     = (float*)   (ws + 5410816);
  float*    x1a     = (float*)   (ws + 7507968);
  float*    x2w     = (float*)   (ws + 9605120);
  ushort_t* x2b     = (ushort_t*)(ws + 11702272);
  float*    S       = (float*)   (ws + 12750848);
  float*    Sinv    = (float*)   (ws + 12783616);

  k_init    <<<32,   256, 0, stream>>>(deg, cnt, wcnt, S);
  k_deg_cnt <<<1024, 256, 0, stream>>>(ei, ew, deg, cnt);
  k_dinv    <<<32,   256, 0, stream>>>(deg, dinv);
  k_scan    <<<1,    256, 0, stream>>>(cnt, rowptr);
  k_fill    <<<1024, 256, 0, stream>>>(ei, ew, dinv, rowptr, wcnt, csr_src, csr_nrm);
  k_pack_w1 <<<2048, 256, 0, stream>>>(W1, w1hi, w1lo);
  k_pack_fcw<<<2048, 256, 0, stream>>>(fcW, fcwp);
  k_gemm1   <<<256,  512, 0, stream>>>(X, w1hi, w1lo, xw1);
  k_agg     <<<2048, 256, 0, stream>>>(xw1, b1, dinv, rowptr, csr_src, csr_nrm, x1a, (ushort_t*)0, 0);
  k_conv2   <<<8192,  64, 0, stream>>>(x1a, W2, x2w);
  k_agg     <<<2048, 256, 0, stream>>>(x2w, b2, dinv, rowptr, csr_src, csr_nrm, (float*)0, x2b, 1);
  k_rowsum  <<<dim3(64,32), 256, 0, stream>>>(x2b, fcwp, fcb, S);
  k_sinv    <<<32,   256, 0, stream>>>(S, Sinv);
  k_passB   <<<dim3(64,32), 256, 0, stream>>>(x2b, fcwp, fcb, Sinv, out);
}

// Round 2
// 300.267 us; speedup vs baseline: 1.0037x; 1.0037x over previous
//
#include <hip/hip_runtime.h>

// TSP_GNN: 2x GCNConv(edge-weighted, self-loops) + FC + row softmax.
// N=8192 nodes, E=262144 edges, H=64.
// R2: 9 kernels (was 14). conv2 fused into agg1; packs+init fused; dinv in scan;
// rowsum/passB use swapped MFMA operands -> float4 stores; sinv inline in passB.

#define NN 8192
#define NE 262144
#define HD 64

typedef float f32x4 __attribute__((ext_vector_type(4)));
typedef short v8s   __attribute__((ext_vector_type(8)));
typedef unsigned short ushort_t;

__device__ __forceinline__ unsigned short bf16_rne(float f){
  union { float f; unsigned u; } v; v.f = f;
  unsigned r = v.u + 0x7fffu + ((v.u >> 16) & 1u);
  return (unsigned short)(r >> 16);
}
__device__ __forceinline__ float bf16_f32(unsigned short h){
  union { unsigned u; float f; } v; v.u = ((unsigned)h) << 16;
  return v.f;
}
__device__ __forceinline__ f32x4 mfma16(v8s a, v8s b, f32x4 c){
  return __builtin_amdgcn_mfma_f32_16x16x32_bf16(a, b, c, 0, 0, 0);
}

// ---------------- prep: init + pack W1 (hi/lo) + pack fcW ----------------
// W1 [8192][64]: idx = ((kb*4+nt)*16+c)*32+kk  (k=kb*32+kk, col=nt*16+c)
// fcW [64][8192]: idx = ((kb*512+cblk)*16+c)*32+kk (k=kb*32+kk, col=cblk*16+c)
__global__ void k_prep0(const float* __restrict__ W1, const float* __restrict__ fcW,
                        ushort_t* w1hi, ushort_t* w1lo, ushort_t* fcwp,
                        float* deg, int* cnt, int* wcnt, float* S){
  int idx = blockIdx.x*blockDim.x + threadIdx.x;   // 0..524287
  if (idx < NN){ deg[idx]=1.0f; cnt[idx]=0; wcnt[idx]=0; S[idx]=0.0f; }
  {
    int kk = idx & 31, c = (idx>>5)&15, nt = (idx>>9)&3, kb = idx>>11;
    int k = kb*32 + kk, col = nt*16 + c;
    float w = W1[(size_t)k*HD + col];
    unsigned short hi = bf16_rne(w);
    w1hi[idx] = hi;
    w1lo[idx] = bf16_rne(w - bf16_f32(hi));
  }
  {
    int kk = idx & 31, c = (idx>>5)&15, cblk = (idx>>9)&511, kb = idx>>18;
    int k = kb*32 + kk, col = cblk*16 + c;
    fcwp[idx] = bf16_rne(fcW[(size_t)k*NN + col]);
  }
}

__global__ void k_deg_cnt(const int* ei, const float* ew, float* deg, int* cnt){
  int e = blockIdx.x*blockDim.x + threadIdx.x;
  if (e < NE){
    int d = ei[NE + e];                 // dst
    atomicAdd(&deg[d], ew[e]);
    atomicAdd(&cnt[d], 1);
  }
}

// single-block: exclusive scan of counts -> rowptr, plus dinv = 1/sqrt(deg)
__global__ void k_scan(const int* cnt, const float* deg, int* rowptr, float* dinv){
  __shared__ int part[256];
  int t = threadIdx.x;
  int loc[32]; int s = 0;
  #pragma unroll
  for (int j=0;j<32;++j){ loc[j] = cnt[t*32+j]; s += loc[j]; }
  part[t] = s; __syncthreads();
  for (int off=1; off<256; off<<=1){
    int v = (t >= off) ? part[t-off] : 0;
    __syncthreads();
    part[t] += v;
    __syncthreads();
  }
  int run = part[t] - s;
  #pragma unroll
  for (int j=0;j<32;++j){ rowptr[t*32+j] = run; run += loc[j]; }
  if (t == 255) rowptr[NN] = run;
  #pragma unroll
  for (int j=0;j<32;++j) dinv[t*32+j] = 1.0f / sqrtf(deg[t*32+j]);
}

__global__ void k_fill(const int* ei, const float* ew, const float* dinv,
                       const int* rowptr, int* wcnt, int* csr_src, float* csr_nrm){
  int e = blockIdx.x*blockDim.x + threadIdx.x;
  if (e < NE){
    int s = ei[e], d = ei[NE+e];
    int slot = rowptr[d] + atomicAdd(&wcnt[d], 1);
    csr_src[slot] = s;
    csr_nrm[slot] = dinv[s] * ew[e] * dinv[d];
  }
}

// ---------------- GEMM1: xw1 = X @ W1 (split-bf16, 3-MFMA) ----------------
__global__ __launch_bounds__(512) void k_gemm1(const float* __restrict__ X,
                                               const ushort_t* __restrict__ w1hi,
                                               const ushort_t* __restrict__ w1lo,
                                               float* __restrict__ xw1){
  int tid = threadIdx.x, lane = tid & 63, w = tid >> 6;
  int r = lane & 15, seg = lane >> 4;
  int row0 = blockIdx.x * 32;
  const float* xr0 = X + (size_t)(row0 + r)     * NN + seg*8;
  const float* xr1 = X + (size_t)(row0 + 16 + r)* NN + seg*8;
  int kbase = w * 1024;

  f32x4 z = {0.f,0.f,0.f,0.f};
  f32x4 acc0[4] = {z,z,z,z};
  f32x4 acc1[4] = {z,z,z,z};

  f32x4 p00 = *(const f32x4*)(xr0 + kbase);
  f32x4 p01 = *(const f32x4*)(xr0 + kbase + 4);
  f32x4 p10 = *(const f32x4*)(xr1 + kbase);
  f32x4 p11 = *(const f32x4*)(xr1 + kbase + 4);

  for (int it = 0; it < 32; ++it){
    int k0 = kbase + it*32;
    int kb = k0 >> 5;
    f32x4 c00=p00, c01=p01, c10=p10, c11=p11;
    if (it < 31){
      int kn = k0 + 32;
      p00 = *(const f32x4*)(xr0 + kn);
      p01 = *(const f32x4*)(xr0 + kn + 4);
      p10 = *(const f32x4*)(xr1 + kn);
      p11 = *(const f32x4*)(xr1 + kn + 4);
    }
    v8s a0h, a0l, a1h, a1l;
    #pragma unroll
    for (int j=0;j<4;++j){
      float f = c00[j]; unsigned short h = bf16_rne(f);
      a0h[j] = (short)h; a0l[j] = (short)bf16_rne(f - bf16_f32(h));
      f = c01[j]; h = bf16_rne(f);
      a0h[4+j] = (short)h; a0l[4+j] = (short)bf16_rne(f - bf16_f32(h));
      f = c10[j]; h = bf16_rne(f);
      a1h[j] = (short)h; a1l[j] = (short)bf16_rne(f - bf16_f32(h));
      f = c11[j]; h = bf16_rne(f);
      a1h[4+j] = (short)h; a1l[4+j] = (short)bf16_rne(f - bf16_f32(h));
    }
    #pragma unroll
    for (int nt=0; nt<4; ++nt){
      size_t boff = ((size_t)(kb*4 + nt)*16 + r)*32 + seg*8;
      v8s bh = *(const v8s*)(w1hi + boff);
      v8s bl = *(const v8s*)(w1lo + boff);
      acc0[nt] = mfma16(a0h, bh, acc0[nt]);
      acc0[nt] = mfma16(a0h, bl, acc0[nt]);
      acc0[nt] = mfma16(a0l, bh, acc0[nt]);
      acc1[nt] = mfma16(a1h, bh, acc1[nt]);
      acc1[nt] = mfma16(a1h, bl, acc1[nt]);
      acc1[nt] = mfma16(a1l, bh, acc1[nt]);
    }
  }

  // reduce 8 K-partials via LDS (pitch 65 -> no bank conflicts)
  __shared__ float red[8][32][65];   // 65 KB
  #pragma unroll
  for (int nt=0; nt<4; ++nt)
    #pragma unroll
    for (int j=0;j<4;++j){
      red[w][4*seg + j][nt*16 + r]      = acc0[nt][j];
      red[w][16 + 4*seg + j][nt*16 + r] = acc1[nt][j];
    }
  __syncthreads();
  for (int o = tid; o < 32*64; o += 512){
    int rr = o >> 6, cc = o & 63;
    float s = 0.f;
    #pragma unroll
    for (int ww=0; ww<8; ++ww) s += red[ww][rr][cc];
    xw1[(size_t)(row0 + rr)*HD + cc] = s;
  }
}

// ---------------- agg1 + conv2 fused ----------------
// per wave: node i. relu(agg(xw1)+b1) -> row in LDS -> row @ W2 (W2 staged in LDS).
__global__ __launch_bounds__(256) void k_agg1c(const float* __restrict__ xin,
                                               const float* __restrict__ b1,
                                               const float* __restrict__ W2,
                                               const float* __restrict__ dinv,
                                               const int* __restrict__ rowptr,
                                               const int* __restrict__ csr_src,
                                               const float* __restrict__ csr_nrm,
                                               float* __restrict__ x2w){
  __shared__ float W2s[64*64];
  __shared__ float rows[4][64];
  int lane = threadIdx.x & 63, w = threadIdx.x >> 6;
  for (int o = threadIdx.x; o < 64*64; o += 256) W2s[o] = W2[o];
  __syncthreads();

  int i = blockIdx.x*4 + w;
  float di = dinv[i];
  float acc = di*di * xin[(size_t)i*HD + lane];
  int e = rowptr[i], e1 = rowptr[i+1];
  for (; e + 1 < e1; e += 2){
    int s0 = csr_src[e], s1 = csr_src[e+1];
    float n0 = csr_nrm[e], n1 = csr_nrm[e+1];
    acc += n0 * xin[(size_t)s0*HD + lane];
    acc += n1 * xin[(size_t)s1*HD + lane];
  }
  if (e < e1) acc += csr_nrm[e] * xin[(size_t)csr_src[e]*HD + lane];
  float v = acc + b1[lane];
  rows[w][lane] = v > 0.f ? v : 0.f;
  __syncthreads();

  float acc2 = 0.f;
  #pragma unroll
  for (int k=0;k<64;++k) acc2 += rows[w][k] * W2s[k*64 + lane];
  x2w[(size_t)i*HD + lane] = acc2;
}

// ---------------- agg2 -> bf16 ----------------
__global__ __launch_bounds__(256) void k_agg2(const float* __restrict__ xin,
                                              const float* __restrict__ b2,
                                              const float* __restrict__ dinv,
                                              const int* __restrict__ rowptr,
                                              const int* __restrict__ csr_src,
                                              const float* __restrict__ csr_nrm,
                                              ushort_t* __restrict__ x2b){
  int lane = threadIdx.x & 63, w = threadIdx.x >> 6;
  int i = blockIdx.x*4 + w;
  float di = dinv[i];
  float acc = di*di * xin[(size_t)i*HD + lane];
  int e = rowptr[i], e1 = rowptr[i+1];
  for (; e + 1 < e1; e += 2){
    int s0 = csr_src[e], s1 = csr_src[e+1];
    float n0 = csr_nrm[e], n1 = csr_nrm[e+1];
    acc += n0 * xin[(size_t)s0*HD + lane];
    acc += n1 * xin[(size_t)s1*HD + lane];
  }
  if (e < e1) acc += csr_nrm[e] * xin[(size_t)csr_src[e]*HD + lane];
  float v = acc + b2[lane];
  v = v > 0.f ? v : 0.f;
  x2b[(size_t)i*HD + lane] = bf16_rne(v);
}

// ---------------- FC + softmax, swapped-operand MFMA ----------------
// mfma(A=fcW-frag, B=x2-frag) computes z^T tile: lane holds node row = lane&15,
// 4 consecutive FC cols = nt*16 + (lane>>4)*4 + j  -> float4 stores.
__global__ __launch_bounds__(256) void k_rowsum(const ushort_t* __restrict__ x2b,
                                                const ushort_t* __restrict__ fcwp,
                                                const float* __restrict__ fcb,
                                                float* __restrict__ S){
  int lane = threadIdx.x & 63, w = threadIdx.x >> 6;
  int r = lane & 15, seg = lane >> 4;
  int row0 = blockIdx.x*128 + w*32;
  const ushort_t* xb = x2b + (size_t)(row0 + r)*HD + seg*8;
  v8s x00 = *(const v8s*)(xb);
  v8s x01 = *(const v8s*)(xb + 32);
  v8s x10 = *(const v8s*)(xb + 16*HD);
  v8s x11 = *(const v8s*)(xb + 16*HD + 32);
  float rp0 = 0.f, rp1 = 0.f;
  for (int cb=0; cb<4; ++cb){
    int colbase = blockIdx.y*256 + cb*64;
    f32x4 z = {0.f,0.f,0.f,0.f};
    f32x4 acc0[4] = {z,z,z,z}, acc1[4] = {z,z,z,z};
    #pragma unroll
    for (int nt=0; nt<4; ++nt){
      int cblk = (colbase >> 4) + nt;
      v8s bA = *(const v8s*)(fcwp + ((size_t)cblk*16 + r)*32 + seg*8);
      v8s bB = *(const v8s*)(fcwp + ((size_t)(512 + cblk)*16 + r)*32 + seg*8);
      acc0[nt] = mfma16(bA, x00, acc0[nt]);
      acc0[nt] = mfma16(bB, x01, acc0[nt]);
      acc1[nt] = mfma16(bA, x10, acc1[nt]);
      acc1[nt] = mfma16(bB, x11, acc1[nt]);
    }
    #pragma unroll
    for (int nt=0; nt<4; ++nt){
      int col = colbase + nt*16 + seg*4;
      f32x4 fb = *(const f32x4*)(fcb + col);
      #pragma unroll
      for (int j=0;j<4;++j){
        rp0 += __expf(acc0[nt][j] + fb[j]);
        rp1 += __expf(acc1[nt][j] + fb[j]);
      }
    }
  }
  rp0 += __shfl_xor(rp0, 16); rp0 += __shfl_xor(rp0, 32);
  rp1 += __shfl_xor(rp1, 16); rp1 += __shfl_xor(rp1, 32);
  if (lane < 16){
    atomicAdd(&S[row0 + lane],      rp0);
    atomicAdd(&S[row0 + 16 + lane], rp1);
  }
}

__global__ __launch_bounds__(256) void k_passB(const ushort_t* __restrict__ x2b,
                                               const ushort_t* __restrict__ fcwp,
                                               const float* __restrict__ fcb,
                                               const float* __restrict__ S,
                                               float* __restrict__ out){
  int lane = threadIdx.x & 63, w = threadIdx.x >> 6;
  int r = lane & 15, seg = lane >> 4;
  int row0 = blockIdx.x*128 + w*32;
  const ushort_t* xb = x2b + (size_t)(row0 + r)*HD + seg*8;
  v8s x00 = *(const v8s*)(xb);
  v8s x01 = *(const v8s*)(xb + 32);
  v8s x10 = *(const v8s*)(xb + 16*HD);
  v8s x11 = *(const v8s*)(xb + 16*HD + 32);
  float si0 = 1.0f / S[row0 + r];
  float si1 = 1.0f / S[row0 + 16 + r];
  float* o0 = out + (size_t)(row0 + r)*NN;
  float* o1 = out + (size_t)(row0 + 16 + r)*NN;
  for (int cb=0; cb<4; ++cb){
    int colbase = blockIdx.y*256 + cb*64;
    f32x4 z = {0.f,0.f,0.f,0.f};
    f32x4 acc0[4] = {z,z,z,z}, acc1[4] = {z,z,z,z};
    #pragma unroll
    for (int nt=0; nt<4; ++nt){
      int cblk = (colbase >> 4) + nt;
      v8s bA = *(const v8s*)(fcwp + ((size_t)cblk*16 + r)*32 + seg*8);
      v8s bB = *(const v8s*)(fcwp + ((size_t)(512 + cblk)*16 + r)*32 + seg*8);
      acc0[nt] = mfma16(bA, x00, acc0[nt]);
      acc0[nt] = mfma16(bB, x01, acc0[nt]);
      acc1[nt] = mfma16(bA, x10, acc1[nt]);
      acc1[nt] = mfma16(bB, x11, acc1[nt]);
    }
    #pragma unroll
    for (int nt=0; nt<4; ++nt){
      int col = colbase + nt*16 + seg*4;
      f32x4 fb = *(const f32x4*)(fcb + col);
      f32x4 v0, v1;
      #pragma unroll
      for (int j=0;j<4;++j){
        v0[j] = __expf(acc0[nt][j] + fb[j]) * si0;
        v1[j] = __expf(acc1[nt][j] + fb[j]) * si1;
      }
      *(f32x4*)(o0 + col) = v0;
      *(f32x4*)(o1 + col) = v1;
    }
  }
}

// ---------------- host ----------------
extern "C" void kernel_launch(void* const* d_in, const int* in_sizes, int n_in,
                              void* d_out, int out_size, void* d_ws, size_t ws_size,
                              hipStream_t stream){
  (void)in_sizes; (void)n_in; (void)out_size; (void)ws_size;
  const int*   ei  = (const int*)  d_in[0];
  const float* ew  = (const float*)d_in[1];
  const float* X   = (const float*)d_in[2];
  const float* W1  = (const float*)d_in[3];
  const float* b1  = (const float*)d_in[4];
  const float* W2  = (const float*)d_in[5];
  const float* b2  = (const float*)d_in[6];
  const float* fcW = (const float*)d_in[7];
  const float* fcb = (const float*)d_in[8];
  float* out = (float*)d_out;
  char*  ws  = (char*)d_ws;

  float*    deg     = (float*)   (ws + 0);
  float*    dinv    = (float*)   (ws + 32768);
  int*      cnt     = (int*)     (ws + 65536);
  int*      wcnt    = (int*)     (ws + 98304);
  int*      rowptr  = (int*)     (ws + 131072);
  int*      csr_src = (int*)     (ws + 167936);
  float*    csr_nrm = (float*)   (ws + 1216512);
  ushort_t* w1hi    = (ushort_t*)(ws + 2265088);
  ushort_t* w1lo    = (ushort_t*)(ws + 3313664);
  ushort_t* fcwp    = (ushort_t*)(ws + 4362240);
  float*    xw1     = (float*)   (ws + 5410816);
  float*    x2w     = (float*)   (ws + 7507968);
  ushort_t* x2b     = (ushort_t*)(ws + 9605120);
  float*    S       = (float*)   (ws + 10653696);

  k_prep0   <<<2048, 256, 0, stream>>>(W1, fcW, w1hi, w1lo, fcwp, deg, cnt, wcnt, S);
  k_deg_cnt <<<1024, 256, 0, stream>>>(ei, ew, deg, cnt);
  k_scan    <<<1,    256, 0, stream>>>(cnt, deg, rowptr, dinv);
  k_fill    <<<1024, 256, 0, stream>>>(ei, ew, dinv, rowptr, wcnt, csr_src, csr_nrm);
  k_gemm1   <<<256,  512, 0, stream>>>(X, w1hi, w1lo, xw1);
  k_agg1c   <<<2048, 256, 0, stream>>>(xw1, b1, W2, dinv, rowptr, csr_src, csr_nrm, x2w);
  k_agg2    <<<2048, 256, 0, stream>>>(x2w, b2, dinv, rowptr, csr_src, csr_nrm, x2b);
  k_rowsum  <<<dim3(64,32), 256, 0, stream>>>(x2b, fcwp, fcb, S);
  k_passB   <<<dim3(64,32), 256, 0, stream>>>(x2b, fcwp, fcb, S, out);
}